// Round 16
// baseline (71.401 us; speedup 1.0000x reference)
//
#include <hip/hip_runtime.h>
#include <hip/hip_fp16.h>

#define N_NODES 100000
#define N_EDGES 1600000
#define F_IN    128
#define F_OUT   32

#define BKT_SHIFT  7
#define BKT_SIZE   128
#define NBKT       782          // ceil(100000/128)
#define BKT_STRIDE 2560         // mean 2046 per bucket, +11 sigma headroom

#define BIN_THREADS 512
#define BIN_TILE    8192
#define EPT         (BIN_TILE / BIN_THREADS)               // 16
#define NTILES      ((N_EDGES + BIN_TILE - 1) / BIN_TILE)  // 196

#define AGG_SPLIT  4
#define SUB        32           // nodes per aggregate block
#define SUB_STRIDE 768          // mean 512/sub-bucket, +11 sigma headroom

typedef _Float16 f16x8 __attribute__((ext_vector_type(8)));
typedef float    f32x4 __attribute__((ext_vector_type(4)));

#define WH_STRIDE 136   // halfs per W column (272 B -> conflict-free b128)

// Fused front-end: blocks [0,NTILES) bin edges by dst>>7 (rank-capture);
// blocks [NTILES, NTILES+NBKT) compute raw hs = fp16(x @ W) via MFMA.
// The two roles are data-independent; bin's scatter latency hides under the
// matmul's x-stream on the same device.
__global__ __launch_bounds__(512) void fused_bin_matmul_kernel(const int* __restrict__ ei,
                                                               int* __restrict__ gcur,
                                                               unsigned int* __restrict__ binned,
                                                               const float4* __restrict__ x4,
                                                               const float* __restrict__ W,
                                                               __half* __restrict__ hs) {
    __shared__ char pool[9216];
    int t = threadIdx.x;

    if (blockIdx.x < NTILES) {
        // ---------------- bin role (R15-exact) ----------------
        int* cnt   = (int*)pool;           // NBKT
        int* gbase = cnt + NBKT;           // NBKT
        for (int b = t; b < NBKT; b += BIN_THREADS) cnt[b] = 0;
        __syncthreads();
        int ebase = blockIdx.x * BIN_TILE;
        unsigned int pk[EPT];
        int rk[EPT];
        short bkt[EPT];
#pragma unroll
        for (int k = 0; k < EPT; ++k) {
            int e = ebase + k * BIN_THREADS + t;
            if (e < N_EDGES) {
                int s = ei[e];
                int d = ei[N_EDGES + e];
                bkt[k] = (short)(d >> BKT_SHIFT);
                pk[k]  = (unsigned)s | ((unsigned)(d & (BKT_SIZE - 1)) << 25);
                rk[k]  = atomicAdd(&cnt[bkt[k]], 1);
            } else {
                bkt[k] = -1;
            }
        }
        __syncthreads();
        for (int b = t; b < NBKT; b += BIN_THREADS)
            if (cnt[b] > 0) gbase[b] = atomicAdd(&gcur[b], cnt[b]);
        __syncthreads();
#pragma unroll
        for (int k = 0; k < EPT; ++k) {
            if (bkt[k] >= 0) {
                int p = gbase[bkt[k]] + rk[k];
                if (p < BKT_STRIDE)
                    binned[(size_t)bkt[k] * BKT_STRIDE + p] = pk[k];
            }
        }
    } else {
        // ---------------- matmul role: hs = fp16(x @ W), raw ----------------
        _Float16* Wh = (_Float16*)pool;    // F_OUT * WH_STRIDE halfs = 8.7 KB
        int b = blockIdx.x - NTILES;
        {
            int col = t & 31, kb = (t >> 5) * 8;
            for (int u = 0; u < 8; ++u)
                Wh[col * WH_STRIDE + kb + u] = (_Float16)W[(kb + u) * F_OUT + col];
        }
        __syncthreads();

        int w = t >> 6, l = t & 63;
        int lr = l & 15, kg = l >> 4;                // A row lane, k-group
        int row = b * 128 + w * 16 + lr;
        const float4* xr = x4 + (size_t)row * 32;
        bool rok = row < N_NODES;

        f16x8 a[4];
#pragma unroll
        for (int ks = 0; ks < 4; ++ks) {
            float4 v0, v1;
            if (rok) {
                v0 = xr[ks * 8 + kg * 2];
                v1 = xr[ks * 8 + kg * 2 + 1];
            } else {
                v0 = make_float4(0, 0, 0, 0);
                v1 = v0;
            }
            f16x8 av;
            av[0] = (_Float16)v0.x; av[1] = (_Float16)v0.y;
            av[2] = (_Float16)v0.z; av[3] = (_Float16)v0.w;
            av[4] = (_Float16)v1.x; av[5] = (_Float16)v1.y;
            av[6] = (_Float16)v1.z; av[7] = (_Float16)v1.w;
            a[ks] = av;
        }

        f32x4 c0 = {0.f, 0.f, 0.f, 0.f}, c1 = {0.f, 0.f, 0.f, 0.f};
#pragma unroll
        for (int ks = 0; ks < 4; ++ks) {
            f16x8 b0 = *(const f16x8*)&Wh[lr * WH_STRIDE + ks * 32 + kg * 8];
            f16x8 b1 = *(const f16x8*)&Wh[(16 + lr) * WH_STRIDE + ks * 32 + kg * 8];
            c0 = __builtin_amdgcn_mfma_f32_16x16x32_f16(a[ks], b0, c0, 0, 0, 0);
            c1 = __builtin_amdgcn_mfma_f32_16x16x32_f16(a[ks], b1, c1, 0, 0, 0);
        }

        // D layout: col = lane&15, row = (lane>>4)*4 + i   [m89-verified]
        int lrow0 = w * 16 + kg * 4;
#pragma unroll
        for (int i = 0; i < 4; ++i) {
            int orow = b * 128 + lrow0 + i;
            if (orow < N_NODES) {
                hs[(size_t)orow * F_OUT + lr]      = (__half)c0[i];
                hs[(size_t)orow * F_OUT + 16 + lr] = (__half)c1[i];
            }
        }
    }
}

// Degrees from binned edges: 128-entry LDS int histogram per bucket.
__global__ __launch_bounds__(256) void dinv_from_bins_kernel(const unsigned int* __restrict__ binned,
                                                             const int* __restrict__ gcur,
                                                             float* __restrict__ dinv) {
    __shared__ int cnt[BKT_SIZE];
    int t = threadIdx.x;
    int b = blockIdx.x;
    if (t < BKT_SIZE) cnt[t] = 0;
    __syncthreads();
    int ne = gcur[b];
    if (ne > BKT_STRIDE) ne = BKT_STRIDE;
    const unsigned int* eb = binned + (size_t)b * BKT_STRIDE;
    for (int i = t; i < ne; i += 256)
        atomicAdd(&cnt[eb[i] >> 25], 1);
    __syncthreads();
    int gnode = b * BKT_SIZE + t;
    if (t < BKT_SIZE && gnode < N_NODES)
        dinv[gnode] = rsqrtf((float)(cnt[t] + 1));
}

__device__ inline void fma4(uint2 u, float w, float& a0, float& a1, float& a2, float& a3) {
    float2 f0 = __half22float2(*(__half2*)&u.x);
    float2 f1 = __half22float2(*(__half2*)&u.y);
    a0 = fmaf(f0.x, w, a0); a1 = fmaf(f0.y, w, a1);
    a2 = fmaf(f1.x, w, a2); a3 = fmaf(f1.y, w, a3);
}

// 4 blocks per bucket, 32 nodes each (grid 3128). Rank-capture counting sort,
// then 8 lanes/node x 8B raw-h gathers with dinv[src] FMA, 8-deep unrolled.
__global__ __launch_bounds__(256) void aggregate_kernel(const unsigned int* __restrict__ binned,
                                                        const int* __restrict__ gcur,
                                                        const uint2* __restrict__ hs4,
                                                        const float* __restrict__ dinv,
                                                        const float* __restrict__ bias,
                                                        float* __restrict__ out) {
    __shared__ int cnt[SUB];
    __shared__ int sc[SUB];
    __shared__ int rp[SUB + 1];
    __shared__ int se[SUB_STRIDE];       // 3 KB
    int t = threadIdx.x;
    int b   = blockIdx.x >> 2;           // bucket
    int sub = blockIdx.x & 3;            // quarter of the bucket
    int ne = gcur[b];
    if (ne > BKT_STRIDE) ne = BKT_STRIDE;
    const unsigned int* eb = binned + (size_t)b * BKT_STRIDE;

    if (t < SUB) cnt[t] = 0;
    __syncthreads();

    unsigned pk[10];
    int rk[10];
#pragma unroll
    for (int k = 0; k < 10; ++k) {
        int i = t + k * 256;
        pk[k] = (i < ne) ? eb[i] : 0xFFFFFFFFu;
    }
#pragma unroll
    for (int k = 0; k < 10; ++k) {
        rk[k] = -1;
        if (pk[k] != 0xFFFFFFFFu) {
            int dl = (int)(pk[k] >> 25);
            if ((dl >> 5) == sub) rk[k] = atomicAdd(&cnt[dl & 31], 1);
        }
    }
    __syncthreads();
    int v = (t < SUB) ? cnt[t] : 0;
    if (t < SUB) sc[t] = v;
    __syncthreads();
    for (int off = 1; off < SUB; off <<= 1) {
        int add = (t < SUB && t >= off) ? sc[t - off] : 0;
        __syncthreads();
        if (t < SUB) sc[t] += add;
        __syncthreads();
    }
    if (t < SUB) {
        int ex = sc[t] - v;              // exclusive prefix
        rp[t] = (ex < SUB_STRIDE) ? ex : SUB_STRIDE;
    }
    if (t == 0) {
        int tot = sc[SUB - 1];
        rp[SUB] = (tot > SUB_STRIDE) ? SUB_STRIDE : tot;
    }
    __syncthreads();
#pragma unroll
    for (int k = 0; k < 10; ++k) {
        if (rk[k] >= 0) {
            int dl = (int)(pk[k] >> 25);
            int pos = rp[dl & 31] + rk[k];
            if (pos < SUB_STRIDE) se[pos] = (int)(pk[k] & 0x1FFFFFF);
        }
    }
    __syncthreads();

    int g = t >> 3, j4 = t & 7;          // 32 nodes x 8 lanes (4 cols/lane)
    int n = g;
    int gnode = b * BKT_SIZE + sub * SUB + n;
    if (gnode >= N_NODES) return;
    float4 bv = *(const float4*)&bias[j4 * 4];
    int deg = cnt[n];
    int beg = rp[n];
    int end = rp[n + 1];
    if (beg + deg < end) end = beg + deg;
    float a0 = 0.f, a1 = 0.f, a2 = 0.f, a3 = 0.f;
    int p = beg;
    for (; p + 7 < end; p += 8) {        // 8 independent 8B gathers in flight
        int s0 = se[p],     s1 = se[p + 1], s2 = se[p + 2], s3 = se[p + 3];
        int s4 = se[p + 4], s5 = se[p + 5], s6 = se[p + 6], s7 = se[p + 7];
        uint2 u0 = hs4[(size_t)s0 * 8 + j4]; float w0 = dinv[s0];
        uint2 u1 = hs4[(size_t)s1 * 8 + j4]; float w1 = dinv[s1];
        uint2 u2 = hs4[(size_t)s2 * 8 + j4]; float w2 = dinv[s2];
        uint2 u3 = hs4[(size_t)s3 * 8 + j4]; float w3 = dinv[s3];
        uint2 u4 = hs4[(size_t)s4 * 8 + j4]; float w4 = dinv[s4];
        uint2 u5 = hs4[(size_t)s5 * 8 + j4]; float w5 = dinv[s5];
        uint2 u6 = hs4[(size_t)s6 * 8 + j4]; float w6 = dinv[s6];
        uint2 u7 = hs4[(size_t)s7 * 8 + j4]; float w7 = dinv[s7];
        fma4(u0, w0, a0, a1, a2, a3); fma4(u1, w1, a0, a1, a2, a3);
        fma4(u2, w2, a0, a1, a2, a3); fma4(u3, w3, a0, a1, a2, a3);
        fma4(u4, w4, a0, a1, a2, a3); fma4(u5, w5, a0, a1, a2, a3);
        fma4(u6, w6, a0, a1, a2, a3); fma4(u7, w7, a0, a1, a2, a3);
    }
    for (; p + 3 < end; p += 4) {
        int s0 = se[p], s1 = se[p + 1], s2 = se[p + 2], s3 = se[p + 3];
        uint2 u0 = hs4[(size_t)s0 * 8 + j4]; float w0 = dinv[s0];
        uint2 u1 = hs4[(size_t)s1 * 8 + j4]; float w1 = dinv[s1];
        uint2 u2 = hs4[(size_t)s2 * 8 + j4]; float w2 = dinv[s2];
        uint2 u3 = hs4[(size_t)s3 * 8 + j4]; float w3 = dinv[s3];
        fma4(u0, w0, a0, a1, a2, a3); fma4(u1, w1, a0, a1, a2, a3);
        fma4(u2, w2, a0, a1, a2, a3); fma4(u3, w3, a0, a1, a2, a3);
    }
    for (; p < end; ++p) {
        int s0 = se[p];
        uint2 u0 = hs4[(size_t)s0 * 8 + j4]; float w0 = dinv[s0];
        fma4(u0, w0, a0, a1, a2, a3);
    }
    float dv = rsqrtf((float)(deg + 1));   // deg counted locally == global
    uint2 us = hs4[(size_t)gnode * 8 + j4];
    float2 s0 = __half22float2(*(__half2*)&us.x);
    float2 s1 = __half22float2(*(__half2*)&us.y);
    float4 o;
    o.x = bv.x + dv * (a0 + dv * s0.x);
    o.y = bv.y + dv * (a1 + dv * s0.y);
    o.z = bv.z + dv * (a2 + dv * s1.x);
    o.w = bv.w + dv * (a3 + dv * s1.y);
    *(float4*)&out[(size_t)gnode * F_OUT + j4 * 4] = o;
}

extern "C" void kernel_launch(void* const* d_in, const int* in_sizes, int n_in,
                              void* d_out, int out_size, void* d_ws, size_t ws_size,
                              hipStream_t stream) {
    const float* x  = (const float*)d_in[0];
    const int*   ei = (const int*)d_in[1];   // int32 on device
    const float* W  = (const float*)d_in[2];
    const float* b  = (const float*)d_in[3];
    float* out = (float*)d_out;

    int*          gcur   = (int*)d_ws;                                    // 1024
    unsigned int* binned = (unsigned int*)(gcur + 1024);                  // 8.0 MB
    float*        dinv   = (float*)(binned + (size_t)NBKT * BKT_STRIDE);  // 400 KB
    __half*       hs     = (__half*)(dinv + ((N_NODES + 3) & ~3));        // 6.4 MB

    hipMemsetAsync(gcur, 0, NBKT * sizeof(int), stream);

    fused_bin_matmul_kernel<<<NTILES + NBKT, 512, 0, stream>>>(ei, gcur, binned,
                                                               (const float4*)x, W, hs);

    dinv_from_bins_kernel<<<NBKT, 256, 0, stream>>>(binned, gcur, dinv);

    aggregate_kernel<<<NBKT * AGG_SPLIT, 256, 0, stream>>>(binned, gcur, (const uint2*)hs,
                                                           dinv, b, out);
}

// Round 17
// 70.160 us; speedup vs baseline: 1.0177x; 1.0177x over previous
//
#include <hip/hip_runtime.h>
#include <hip/hip_fp16.h>

#define N_NODES 100000
#define N_EDGES 1600000
#define F_IN    128
#define F_OUT   32

#define BKT_SHIFT  7
#define BKT_SIZE   128
#define NBKT       782          // ceil(100000/128)
#define BKT_STRIDE 2560         // mean 2046 per bucket, +11 sigma headroom

#define BIN_THREADS 512
#define BIN_TILE    8192
#define EPT         (BIN_TILE / BIN_THREADS)               // 16
#define NTILES      ((N_EDGES + BIN_TILE - 1) / BIN_TILE)  // 196

#define AGG_SPLIT  4
#define SUB        32           // nodes per aggregate block
#define SUB_STRIDE 768          // mean 512/sub-bucket, +11 sigma headroom

typedef _Float16 f16x8 __attribute__((ext_vector_type(8)));
typedef float    f32x4 __attribute__((ext_vector_type(4)));

// Bin edges by dst>>7 into 782 buckets. Rank-capture: one LDS atomic per edge
// gives both the histogram and the in-tile rank. [R11-exact]
__global__ __launch_bounds__(BIN_THREADS) void bin_kernel(const int* __restrict__ ei,
                                                          int* __restrict__ gcur,
                                                          unsigned int* __restrict__ binned) {
    __shared__ int cnt[NBKT], gbase[NBKT];
    int t = threadIdx.x;
    for (int b = t; b < NBKT; b += BIN_THREADS) cnt[b] = 0;
    __syncthreads();
    int ebase = blockIdx.x * BIN_TILE;
    unsigned int pk[EPT];
    int rk[EPT];
    short bkt[EPT];
#pragma unroll
    for (int k = 0; k < EPT; ++k) {
        int e = ebase + k * BIN_THREADS + t;
        if (e < N_EDGES) {
            int s = ei[e];
            int d = ei[N_EDGES + e];
            bkt[k] = (short)(d >> BKT_SHIFT);
            pk[k]  = (unsigned)s | ((unsigned)(d & (BKT_SIZE - 1)) << 25);
            rk[k]  = atomicAdd(&cnt[bkt[k]], 1);
        } else {
            bkt[k] = -1;
        }
    }
    __syncthreads();
    for (int b = t; b < NBKT; b += BIN_THREADS)
        if (cnt[b] > 0) gbase[b] = atomicAdd(&gcur[b], cnt[b]);
    __syncthreads();
#pragma unroll
    for (int k = 0; k < EPT; ++k) {
        if (bkt[k] >= 0) {
            int p = gbase[bkt[k]] + rk[k];
            if (p < BKT_STRIDE)
                binned[(size_t)bkt[k] * BKT_STRIDE + p] = pk[k];
        }
    }
}

// Fused: per-bucket degree histogram (-> dinv in LDS) + MFMA matmul for the
// bucket's 128 rows. hs = fp16( (x @ W) * dinv[row] ).  [R11-exact]
#define WH_STRIDE 136   // halfs per W column (272 B -> conflict-free b128)
__global__ __launch_bounds__(512) void matmul_kernel(const float4* __restrict__ x4,
                                                     const float* __restrict__ W,
                                                     const unsigned int* __restrict__ binned,
                                                     const int* __restrict__ gcur,
                                                     __half* __restrict__ hs) {
    __shared__ _Float16 Wh[F_OUT * WH_STRIDE];   // 8.7 KB, [col][k]
    __shared__ int cnt128[BKT_SIZE];
    __shared__ float dinvL[BKT_SIZE];
    int t = threadIdx.x;
    int b = blockIdx.x;

    if (t < BKT_SIZE) cnt128[t] = 0;
    {
        int col = t & 31, kb = (t >> 5) * 8;
        for (int u = 0; u < 8; ++u)
            Wh[col * WH_STRIDE + kb + u] = (_Float16)W[(kb + u) * F_OUT + col];
    }
    __syncthreads();

    int ne = gcur[b];
    if (ne > BKT_STRIDE) ne = BKT_STRIDE;
    const unsigned int* eb = binned + (size_t)b * BKT_STRIDE;
    for (int i = t; i < ne; i += 512)
        atomicAdd(&cnt128[eb[i] >> 25], 1);
    __syncthreads();
    if (t < BKT_SIZE) dinvL[t] = rsqrtf((float)(cnt128[t] + 1));  // +1 self loop
    __syncthreads();

    int w = t >> 6, l = t & 63;
    int lr = l & 15, kg = l >> 4;                // A row lane, k-group
    int row = b * 128 + w * 16 + lr;
    const float4* xr = x4 + (size_t)row * 32;
    bool rok = row < N_NODES;

    f16x8 a[4];
#pragma unroll
    for (int ks = 0; ks < 4; ++ks) {
        float4 v0, v1;
        if (rok) {
            v0 = xr[ks * 8 + kg * 2];
            v1 = xr[ks * 8 + kg * 2 + 1];
        } else {
            v0 = make_float4(0, 0, 0, 0);
            v1 = v0;
        }
        f16x8 av;
        av[0] = (_Float16)v0.x; av[1] = (_Float16)v0.y;
        av[2] = (_Float16)v0.z; av[3] = (_Float16)v0.w;
        av[4] = (_Float16)v1.x; av[5] = (_Float16)v1.y;
        av[6] = (_Float16)v1.z; av[7] = (_Float16)v1.w;
        a[ks] = av;
    }

    f32x4 c0 = {0.f, 0.f, 0.f, 0.f}, c1 = {0.f, 0.f, 0.f, 0.f};
#pragma unroll
    for (int ks = 0; ks < 4; ++ks) {
        f16x8 b0 = *(const f16x8*)&Wh[lr * WH_STRIDE + ks * 32 + kg * 8];
        f16x8 b1 = *(const f16x8*)&Wh[(16 + lr) * WH_STRIDE + ks * 32 + kg * 8];
        c0 = __builtin_amdgcn_mfma_f32_16x16x32_f16(a[ks], b0, c0, 0, 0, 0);
        c1 = __builtin_amdgcn_mfma_f32_16x16x32_f16(a[ks], b1, c1, 0, 0, 0);
    }

    // D layout: col = lane&15, row = (lane>>4)*4 + i   [m89-verified]
    int lrow0 = w * 16 + kg * 4;
#pragma unroll
    for (int i = 0; i < 4; ++i) {
        int orow = b * 128 + lrow0 + i;
        if (orow < N_NODES) {
            float dv = dinvL[lrow0 + i];
            hs[(size_t)orow * F_OUT + lr]      = (__half)(c0[i] * dv);
            hs[(size_t)orow * F_OUT + 16 + lr] = (__half)(c1[i] * dv);
        }
    }
}

__device__ inline void acc4(uint2 u, float& a0, float& a1, float& a2, float& a3) {
    float2 f0 = __half22float2(*(__half2*)&u.x);
    float2 f1 = __half22float2(*(__half2*)&u.y);
    a0 += f0.x; a1 += f0.y; a2 += f1.x; a3 += f1.y;
}

// 4 blocks per bucket, 32 nodes each (grid 3128). Rank-capture counting sort
// + degree-descending node->lane-group permutation so each wave's 8 nodes
// have near-equal degree (kills max-deg divergence), then 8 lanes/node x 8B
// gathers, 8-deep unrolled.  [R11 + order only]
__global__ __launch_bounds__(256) void aggregate_kernel(const unsigned int* __restrict__ binned,
                                                        const int* __restrict__ gcur,
                                                        const uint2* __restrict__ hs4,
                                                        const float* __restrict__ bias,
                                                        float* __restrict__ out) {
    __shared__ int cnt[SUB];
    __shared__ int sc[SUB];
    __shared__ int rp[SUB + 1];
    __shared__ int order[SUB];
    __shared__ int se[SUB_STRIDE];       // 3 KB
    int t = threadIdx.x;
    int b   = blockIdx.x >> 2;           // bucket
    int sub = blockIdx.x & 3;            // quarter of the bucket
    int ne = gcur[b];
    if (ne > BKT_STRIDE) ne = BKT_STRIDE;
    const unsigned int* eb = binned + (size_t)b * BKT_STRIDE;

    if (t < SUB) cnt[t] = 0;
    __syncthreads();

    unsigned pk[10];
    int rk[10];
#pragma unroll
    for (int k = 0; k < 10; ++k) {
        int i = t + k * 256;
        pk[k] = (i < ne) ? eb[i] : 0xFFFFFFFFu;
    }
#pragma unroll
    for (int k = 0; k < 10; ++k) {
        rk[k] = -1;
        if (pk[k] != 0xFFFFFFFFu) {
            int dl = (int)(pk[k] >> 25);
            if ((dl >> 5) == sub) rk[k] = atomicAdd(&cnt[dl & 31], 1);
        }
    }
    __syncthreads();
    int v = (t < SUB) ? cnt[t] : 0;
    if (t < SUB) sc[t] = v;
    __syncthreads();
    for (int off = 1; off < SUB; off <<= 1) {
        int add = (t < SUB && t >= off) ? sc[t - off] : 0;
        __syncthreads();
        if (t < SUB) sc[t] += add;
        __syncthreads();
    }
    if (t < SUB) {
        int ex = sc[t] - v;              // exclusive prefix
        rp[t] = (ex < SUB_STRIDE) ? ex : SUB_STRIDE;
        // degree-descending rank: r = #nodes with (deg,idx) ordered before t
        int r = 0;
#pragma unroll 8
        for (int j = 0; j < SUB; ++j) {
            int dj = cnt[j];
            r += (dj > v) || (dj == v && j < t);
        }
        order[r] = t;
    }
    if (t == 0) {
        int tot = sc[SUB - 1];
        rp[SUB] = (tot > SUB_STRIDE) ? SUB_STRIDE : tot;
    }
    __syncthreads();
#pragma unroll
    for (int k = 0; k < 10; ++k) {
        if (rk[k] >= 0) {
            int dl = (int)(pk[k] >> 25);
            int pos = rp[dl & 31] + rk[k];
            if (pos < SUB_STRIDE) se[pos] = (int)(pk[k] & 0x1FFFFFF);
        }
    }
    __syncthreads();

    int g = t >> 3, j4 = t & 7;          // 32 groups x 8 lanes (4 cols/lane)
    int n = order[g];                    // degree-balanced assignment
    int gnode = b * BKT_SIZE + sub * SUB + n;
    if (gnode >= N_NODES) return;
    float4 bv = *(const float4*)&bias[j4 * 4];
    int deg = cnt[n];
    int beg = rp[n];
    int end = rp[n + 1];
    if (beg + deg < end) end = beg + deg;
    float a0 = 0.f, a1 = 0.f, a2 = 0.f, a3 = 0.f;
    int p = beg;
    for (; p + 7 < end; p += 8) {        // 8 independent 8B gathers in flight
        uint2 u0 = hs4[(size_t)se[p]     * 8 + j4];
        uint2 u1 = hs4[(size_t)se[p + 1] * 8 + j4];
        uint2 u2 = hs4[(size_t)se[p + 2] * 8 + j4];
        uint2 u3 = hs4[(size_t)se[p + 3] * 8 + j4];
        uint2 u4 = hs4[(size_t)se[p + 4] * 8 + j4];
        uint2 u5 = hs4[(size_t)se[p + 5] * 8 + j4];
        uint2 u6 = hs4[(size_t)se[p + 6] * 8 + j4];
        uint2 u7 = hs4[(size_t)se[p + 7] * 8 + j4];
        acc4(u0, a0, a1, a2, a3); acc4(u1, a0, a1, a2, a3);
        acc4(u2, a0, a1, a2, a3); acc4(u3, a0, a1, a2, a3);
        acc4(u4, a0, a1, a2, a3); acc4(u5, a0, a1, a2, a3);
        acc4(u6, a0, a1, a2, a3); acc4(u7, a0, a1, a2, a3);
    }
    for (; p + 3 < end; p += 4) {
        uint2 u0 = hs4[(size_t)se[p]     * 8 + j4];
        uint2 u1 = hs4[(size_t)se[p + 1] * 8 + j4];
        uint2 u2 = hs4[(size_t)se[p + 2] * 8 + j4];
        uint2 u3 = hs4[(size_t)se[p + 3] * 8 + j4];
        acc4(u0, a0, a1, a2, a3); acc4(u1, a0, a1, a2, a3);
        acc4(u2, a0, a1, a2, a3); acc4(u3, a0, a1, a2, a3);
    }
    for (; p < end; ++p) {
        uint2 u0 = hs4[(size_t)se[p] * 8 + j4];
        acc4(u0, a0, a1, a2, a3);
    }
    float dv = rsqrtf((float)(deg + 1));   // same value matmul folded for src
    uint2 us = hs4[(size_t)gnode * 8 + j4];
    float2 s0 = __half22float2(*(__half2*)&us.x);
    float2 s1 = __half22float2(*(__half2*)&us.y);
    float4 o;
    o.x = bv.x + dv * (a0 + s0.x);
    o.y = bv.y + dv * (a1 + s0.y);
    o.z = bv.z + dv * (a2 + s1.x);
    o.w = bv.w + dv * (a3 + s1.y);
    *(float4*)&out[(size_t)gnode * F_OUT + j4 * 4] = o;
}

extern "C" void kernel_launch(void* const* d_in, const int* in_sizes, int n_in,
                              void* d_out, int out_size, void* d_ws, size_t ws_size,
                              hipStream_t stream) {
    const float* x  = (const float*)d_in[0];
    const int*   ei = (const int*)d_in[1];   // int32 on device
    const float* W  = (const float*)d_in[2];
    const float* b  = (const float*)d_in[3];
    float* out = (float*)d_out;

    int*          gcur   = (int*)d_ws;                       // pad to 1024
    unsigned int* binned = (unsigned int*)(gcur + 1024);     // NBKT*BKT_STRIDE ~8 MB
    __half*       hs     = (__half*)(binned + (size_t)NBKT * BKT_STRIDE);  // 6.4 MB

    hipMemsetAsync(gcur, 0, NBKT * sizeof(int), stream);

    bin_kernel<<<NTILES, BIN_THREADS, 0, stream>>>(ei, gcur, binned);

    matmul_kernel<<<NBKT, 512, 0, stream>>>((const float4*)x, W, binned, gcur, hs);

    aggregate_kernel<<<NBKT * AGG_SPLIT, 256, 0, stream>>>(binned, gcur, (const uint2*)hs, b, out);
}